// Round 5
// baseline (1465.311 us; speedup 1.0000x reference)
//
#include <hip/hip_runtime.h>
#include <hip/hip_bf16.h>
#include <math.h>

// Problem constants (Encoder_16750372454478)
#define D_MODEL 1024
#define HEADS   16
#define DKV     64
#define LAYERS  4
#define BATCH   8
#define SEQ     1024
#define NTOK    (BATCH*SEQ)      // 8192
#define LN_N    (SEQ*D_MODEL)    // per-sample LN element count
#define EPSV    1e-5f

typedef __attribute__((ext_vector_type(8))) short short8;   // 8 bf16 (4 VGPRs)
typedef __attribute__((ext_vector_type(4))) float floatx4;

__device__ __forceinline__ float bf2f(ushort u) {
    union { uint i; float f; } v; v.i = ((uint)u) << 16; return v.f;
}
__device__ __forceinline__ ushort f2bf(float f) {
    union { float f; uint i; } v; v.f = f;
    uint r = (v.i + 0x7fffu + ((v.i >> 16) & 1u)) >> 16;   // round-nearest-even
    return (ushort)r;
}
// pack two f32 -> one u32 of 2 bf16 (low = a, high = b). T12 recipe (no builtin).
__device__ __forceinline__ uint cvtpk(float a, float b) {
    uint r;
    asm("v_cvt_pk_bf16_f32 %0, %1, %2" : "=v"(r) : "v"(a), "v"(b));
    return r;
}
// permlane swaps (gfx950): a/c both read+written.
__device__ __forceinline__ void pl32(uint &a, uint &c) {
    asm volatile("v_permlane32_swap_b32 %0, %1" : "+v"(a), "+v"(c));
}
__device__ __forceinline__ void pl16(uint &a, uint &c) {
    asm volatile("v_permlane16_swap_b32 %0, %1" : "+v"(a), "+v"(c));
}

// async global->LDS, 16 B per lane (LDS dest = wave-uniform base + lane*16).
__device__ __forceinline__ void gload16(const ushort* g, ushort* l) {
    __builtin_amdgcn_global_load_lds(
        (const __attribute__((address_space(1))) void*)g,
        (__attribute__((address_space(3))) void*)l, 16, 0, 0);
}

// ---------------------------------------------------------------------------
// GEMM core, 4-deep counted-vmcnt pipeline (T4, AITER-style derived waits):
// C[128x128], BK=32, 4 waves (2x2), 64x64 each, K = D_MODEL (32 steps).
// LDS = 4 circular buffers x (A 8KB + B 8KB) = 64KB -> 2 blocks/CU.
// Per step t: wait vmcnt(8) [tile t's 4 loads retire; t+1/t+2's 8 stay in
// flight], s_barrier, issue tile t+3's loads, ds_read frags, 16 MFMA.
// Loads get 3 K-steps of latency budget; vmcnt never drains to 0 mid-loop.
// Swizzle: physical chunk cp of row r holds logical chunk cp^((r>>1)&3)
// (both-sides XOR, rule #21). bank(r)=(16r+4c)%32 injective over r mod 8
// -> ds_read_b128 2-way (free). Epilogue waits: vmcnt(4)@NK-2, vmcnt(0)@NK-1.
// ---------------------------------------------------------------------------
#define TB32 (128*32)   // elements per buffer (8KB)
__device__ __forceinline__ void gemm_core_p4(
    const ushort* __restrict__ A, const ushort* __restrict__ B,
    int lda, int ldb,
    ushort* ldsA, ushort* ldsB, floatx4 (&acc)[4][4])
{
    constexpr int NK = D_MODEL / 32;      // 32 K-steps
    const int tid = threadIdx.x, lane = tid & 63, w = tid >> 6;
    const int wm = w >> 1, wn = w & 1;
    const int mn = lane & 15, quad = lane >> 4;

    // staging coords: chunk lin = s*256+tid (s=0,1); r = lin>>2, cp = lin&3.
    // source chunk = cp ^ ((r>>1)&3); halves differ by 64 rows (same XOR).
    const int r0 = tid >> 2, cp0 = tid & 3;
    const int csrc = (cp0 ^ ((r0 >> 1) & 3)) * 8;
    const ushort* gA0 = A + (size_t)r0 * lda + csrc;
    const ushort* gA1 = gA0 + (size_t)64 * lda;
    const ushort* gB0 = B + (size_t)r0 * ldb + csrc;
    const ushort* gB1 = gB0 + (size_t)64 * ldb;
    ushort* lA0 = ldsA + tid * 8;
    ushort* lB0 = ldsB + tid * 8;

    auto stage = [&](int t) {
        const int bo = (t & 3) * TB32;
        const int k0 = t * 32;
        gload16(gA0 + k0, lA0 + bo);
        gload16(gA1 + k0, lA0 + bo + 2048);
        gload16(gB0 + k0, lB0 + bo);
        gload16(gB1 + k0, lB0 + bo + 2048);
    };

    stage(0); stage(1); stage(2);

    // per-lane read chunk: logical chunk quad at row r -> physical
    // quad ^ ((r>>1)&3); (r>>1)&3 == (mn>>1)&3 for all fragment rows.
    const int crd = (quad ^ ((mn >> 1) & 3)) * 8;

#pragma unroll 1
    for (int t = 0; t < NK; ++t) {
        if (t < NK - 2)       asm volatile("s_waitcnt vmcnt(8)" ::: "memory");
        else if (t == NK - 2) asm volatile("s_waitcnt vmcnt(4)" ::: "memory");
        else                  asm volatile("s_waitcnt vmcnt(0)" ::: "memory");
        __builtin_amdgcn_s_barrier();
        __builtin_amdgcn_sched_barrier(0);
        if (t + 3 < NK) stage(t + 3);
        __builtin_amdgcn_sched_barrier(0);   // pin load issue before ds_reads
        const ushort* cA = ldsA + (t & 3) * TB32;
        const ushort* cB = ldsB + (t & 3) * TB32;
        short8 af[4], bfr[4];
#pragma unroll
        for (int i = 0; i < 4; i++)
            af[i] = *(const short8*)(cA + (wm * 64 + i * 16 + mn) * 32 + crd);
#pragma unroll
        for (int j = 0; j < 4; j++)
            bfr[j] = *(const short8*)(cB + (wn * 64 + j * 16 + mn) * 32 + crd);
        __builtin_amdgcn_s_setprio(1);
#pragma unroll
        for (int i = 0; i < 4; i++)
#pragma unroll
            for (int j = 0; j < 4; j++)
                acc[i][j] = __builtin_amdgcn_mfma_f32_16x16x32_bf16(af[i], bfr[j], acc[i][j], 0, 0, 0);
        __builtin_amdgcn_s_setprio(0);
    }
}

// ---------------------------------------------------------------------------
// Generic GEMM: out = f(A[M,K] B[N,K]^T) with optional fused epilogues:
//  - lnIn+csum: algebraic LN: out = r*(acc - mean*colsum_j) + bias_j
//  - bias, relu
//  - resid: v += resid[elem]; per-sample sum/sumsq atomically -> statsOut
//  - outF: write fp32 instead of bf16
// XCD-chunked swizzle, y-fastest. stats layout: [smp]=sum, [32+smp]=sumsq.
// ---------------------------------------------------------------------------
__global__ __launch_bounds__(256) void gemm_bt128(
    const ushort* __restrict__ A, const ushort* __restrict__ B,
    const float* __restrict__ bias, ushort* __restrict__ C,
    const ushort* __restrict__ resid, float* __restrict__ statsOut,
    float* __restrict__ outF, int relu,
    const float* __restrict__ lnIn, const float* __restrict__ csum)
{
    __shared__ ushort ldsA[4 * TB32], ldsB[4 * TB32];
    __shared__ float sred1[4], sred2[4];
    const int lid = blockIdx.y * 64 + blockIdx.x;
    const int xcd = lid & 7, idx = lid >> 3;          // idx in [0,64)
    const int bx = xcd * 8 + (idx >> 3);              // 8 x-tiles per XCD
    const int by = idx & 7;                           // y fastest
    floatx4 acc[4][4];
#pragma unroll
    for (int i = 0; i < 4; i++)
#pragma unroll
        for (int j = 0; j < 4; j++) acc[i][j] = (floatx4){0.f, 0.f, 0.f, 0.f};

    gemm_core_p4(A + (size_t)bx * 128 * D_MODEL,
                 B + (size_t)by * 128 * D_MODEL,
                 D_MODEL, D_MODEL, ldsA, ldsB, acc);

    const int lane = threadIdx.x & 63, w = threadIdx.x >> 6;
    const int wm = w >> 1, wn = w & 1;
    const int mn = lane & 15, quad = lane >> 4;
    const int bsmp = bx >> 3;                         // sample (128 | SEQ)
    float mean = 0.f, rln = 1.f;
    if (lnIn) {
        float sum = lnIn[bsmp], sq = lnIn[32 + bsmp];
        mean = sum * (1.f / (float)LN_N);
        rln  = rsqrtf(sq * (1.f / (float)LN_N) - mean * mean + EPSV);
    }
    float ssum = 0.f, ssq = 0.f;
#pragma unroll
    for (int i = 0; i < 4; i++) {
#pragma unroll
        for (int j = 0; j < 4; j++) {
            int col = by * 128 + wn * 64 + j * 16 + mn;
            float bv = bias ? bias[col] : 0.f;
            float cj = csum ? csum[col] : 0.f;
#pragma unroll
            for (int r = 0; r < 4; r++) {
                int row = bx * 128 + wm * 64 + i * 16 + quad * 4 + r;
                float v = acc[i][j][r];
                if (lnIn) v = (v - mean * cj) * rln;
                v += bv;
                if (relu) v = fmaxf(v, 0.f);
                if (resid) {
                    v += bf2f(resid[(size_t)row * D_MODEL + col]);
                    ssum += v; ssq += v * v;
                }
                if (outF) outF[(size_t)row * D_MODEL + col] = v;
                else      C[(size_t)row * D_MODEL + col] = f2bf(v);
            }
        }
    }
    if (statsOut) {
        for (int o = 1; o < 64; o <<= 1) {
            ssum += __shfl_xor(ssum, o); ssq += __shfl_xor(ssq, o);
        }
        if (lane == 0) { sred1[w] = ssum; sred2[w] = ssq; }
        __syncthreads();
        if (threadIdx.x == 0) {
            atomicAdd(&statsOut[bsmp],      sred1[0] + sred1[1] + sred1[2] + sred1[3]);
            atomicAdd(&statsOut[32 + bsmp], sred2[0] + sred2[1] + sred2[2] + sred2[3]);
        }
    }
}

// ---------------------------------------------------------------------------
// Fused Q/K/V projection. Q pre-scaled by 1/8 in the fp32 epilogue. V stored
// transposed per head with packed 8B stores.
// ---------------------------------------------------------------------------
__global__ __launch_bounds__(256) void gemm_qkv(
    const ushort* __restrict__ X, const ushort* __restrict__ Wq,
    const ushort* __restrict__ Wk, const ushort* __restrict__ Wv,
    ushort* __restrict__ Q, ushort* __restrict__ K, ushort* __restrict__ Vt)
{
    __shared__ ushort ldsA[4 * TB32], ldsB[4 * TB32];
    const int lid = blockIdx.y * 64 + blockIdx.x;     // grid (64,24)
    const int xcd = lid & 7, idx = lid >> 3;          // idx in [0,192)
    const int bx = xcd * 8 + idx / 24;                // 8 x-tiles per XCD
    const int byy = idx % 24;                         // y fastest
    const int which = byy >> 3;
    const int nb = byy & 7;
    const ushort* B = (which == 0) ? Wq : (which == 1) ? Wk : Wv;
    floatx4 acc[4][4];
#pragma unroll
    for (int i = 0; i < 4; i++)
#pragma unroll
        for (int j = 0; j < 4; j++) acc[i][j] = (floatx4){0.f, 0.f, 0.f, 0.f};

    gemm_core_p4(X + (size_t)bx * 128 * D_MODEL,
                 B + (size_t)nb * 128 * D_MODEL,
                 D_MODEL, D_MODEL, ldsA, ldsB, acc);

    const int lane = threadIdx.x & 63, w = threadIdx.x >> 6;
    const int wm = w >> 1, wn = w & 1;
    const int mn = lane & 15, quad = lane >> 4;
    if (which == 2) {
        // Vt[(b*H+h)*DKV+kk][t]: r = consecutive t -> pack 4 bf16 = 8B store
#pragma unroll
        for (int i = 0; i < 4; i++) {
#pragma unroll
            for (int j = 0; j < 4; j++) {
                int col = nb * 128 + wn * 64 + j * 16 + mn;
                int h = col >> 6, kk = col & 63;
                int row0 = bx * 128 + wm * 64 + i * 16 + quad * 4;
                int b = row0 >> 10, t0 = row0 & 1023;
                uint2 uu;
                uu.x = cvtpk(acc[i][j][0], acc[i][j][1]);
                uu.y = cvtpk(acc[i][j][2], acc[i][j][3]);
                *(uint2*)(Vt + (((size_t)(b * HEADS + h)) * DKV + kk) * SEQ + t0) = uu;
            }
        }
    } else {
        ushort* dst = (which == 0) ? Q : K;
        const float scl = (which == 0) ? 0.125f : 1.0f;   // Q pre-scale (exact pow2)
#pragma unroll
        for (int i = 0; i < 4; i++) {
#pragma unroll
            for (int j = 0; j < 4; j++) {
                int col = nb * 128 + wn * 64 + j * 16 + mn;
#pragma unroll
                for (int r = 0; r < 4; r++) {
                    int row = bx * 128 + wm * 64 + i * 16 + quad * 4 + r;
                    dst[(size_t)row * D_MODEL + col] = f2bf(acc[i][j][r] * scl);
                }
            }
        }
    }
}

// ---------------------------------------------------------------------------
// Flash attention v3 (unchanged): swapped-QK^T + in-register P (permlane),
// zero staging VGPRs (global_load_lds), 32KB LDS.
// ---------------------------------------------------------------------------
__global__ __launch_bounds__(256) void flash_attn(
    const ushort* __restrict__ Q, const ushort* __restrict__ K,
    const ushort* __restrict__ Vt, ushort* __restrict__ O)
{
    __shared__ ushort lK[64 * 128];   // folded K tile, 16KB
    __shared__ ushort lV[64 * 128];   // V tile, 16KB
    const int tid = threadIdx.x, lane = tid & 63, w = tid >> 6;
    const int mn = lane & 15, quad = lane >> 4;
    const int pair = blockIdx.x;        // 0..127
    const int qt = blockIdx.y;          // 0..7
    const int b = pair >> 4, h = pair & 15;
    const ushort* Qb = Q + ((size_t)b * SEQ) * D_MODEL + h * DKV;
    const ushort* Kb = K + ((size_t)b * SEQ) * D_MODEL + h * DKV;
    const ushort* Vb = Vt + (size_t)pair * DKV * SEQ;

    // Q B-fragments straight from global (already scaled by 1/8)
    short8 bq[2][2];
#pragma unroll
    for (int i = 0; i < 2; i++)
#pragma unroll
        for (int kk = 0; kk < 2; kk++)
            bq[i][kk] = *(const short8*)(Qb +
                (size_t)(qt * 128 + w * 32 + i * 16 + mn) * D_MODEL + kk * 32 + quad * 8);

    auto stage_K = [&](int tkk) {
#pragma unroll
        for (int c = 0; c < 4; c++) {
            int lin = c * 256 + tid;          // 16B chunk index 0..1023
            int rw = lin >> 4;                // folded row' 0..63
            int cc0 = (lin & 15) ^ (rw & 7);  // unswizzled chunk
            int r = rw + ((cc0 >> 3) << 6);   // orig key-row 0..127
            gload16(Kb + (size_t)(tkk * 128 + r) * D_MODEL + (cc0 & 7) * 8,
                    lK + lin * 8);
        }
    };
    auto stage_V = [&](int tkk) {
#pragma unroll
        for (int c = 0; c < 4; c++) {
            int lin = c * 256 + tid;
            int rw = lin >> 4;                // d-row 0..63
            int cc0 = (lin & 15) ^ (rw & 7);
            gload16(Vb + (size_t)rw * SEQ + tkk * 128 + cc0 * 8,
                    lV + lin * 8);
        }
    };

    stage_K(0); stage_V(0);
    __syncthreads();

    floatx4 acc_o[2][4];
    float lrow[2] = {0.f, 0.f};
#pragma unroll
    for (int i = 0; i < 2; i++)
#pragma unroll
        for (int jo = 0; jo < 4; jo++) acc_o[i][jo] = (floatx4){0.f, 0.f, 0.f, 0.f};

    for (int tk = 0; tk < 8; tk++) {
        // ---- QK: S^T = mfma(K, Q/8)
        floatx4 s[2][8];
#pragma unroll
        for (int i = 0; i < 2; i++)
#pragma unroll
            for (int j = 0; j < 8; j++) s[i][j] = (floatx4){0.f, 0.f, 0.f, 0.f};
        __builtin_amdgcn_s_setprio(1);
#pragma unroll
        for (int kk = 0; kk < 2; kk++) {
#pragma unroll
            for (int j = 0; j < 8; j++) {
                int krow = (j & 3) * 16 + mn;
                int kch = (((j >> 2) * 8 + kk * 4 + quad) ^ (mn & 7));
                short8 ak = *(const short8*)(lK + krow * 128 + kch * 8);
                s[0][j] = __builtin_amdgcn_mfma_f32_16x16x32_bf16(ak, bq[0][kk], s[0][j], 0, 0, 0);
                s[1][j] = __builtin_amdgcn_mfma_f32_16x16x32_bf16(ak, bq[1][kk], s[1][j], 0, 0, 0);
            }
        }
        __builtin_amdgcn_s_setprio(0);
        __syncthreads();
        if (tk < 7) stage_K(tk + 1);

        // ---- softmax numerator + bf16 pack
        uint pw[2][8][2];
#pragma unroll
        for (int i = 0; i < 2; i++) {
            float ps = 0.f;
#pragma unroll
            for (int j = 0; j < 8; j++) {
                float p0 = __expf(s[i][j][0]), p1 = __expf(s[i][j][1]);
                float p2 = __expf(s[i][j][2]), p3 = __expf(s[i][j][3]);
                ps += (p0 + p1) + (p2 + p3);
                pw[i][j][0] = cvtpk(p0, p1);
                pw[i][j][1] = cvtpk(p2, p3);
            }
            ps += __shfl_xor(ps, 16);
            ps += __shfl_xor(ps, 32);
            lrow[i] += ps;
        }

        // ---- PV: in-register P redistribution + MFMA
        __builtin_amdgcn_s_setprio(1);
#pragma unroll
        for (int kk = 0; kk < 4; kk++) {
            union { short8 s8; uint u[4]; } pa[2];
#pragma unroll
            for (int i = 0; i < 2; i++) {
                uint A = pw[i][2 * kk][0],     Bw = pw[i][2 * kk][1];
                uint C = pw[i][2 * kk + 1][0], D  = pw[i][2 * kk + 1][1];
                pl32(A, C);  pl16(A, C);
                pl32(Bw, D); pl16(Bw, D);
                pa[i].u[0] = A; pa[i].u[1] = Bw; pa[i].u[2] = C; pa[i].u[3] = D;
            }
#pragma unroll
            for (int jo = 0; jo < 4; jo++) {
                int vch = ((kk * 4 + quad) ^ (mn & 7));
                short8 bv = *(const short8*)(lV + (jo * 16 + mn) * 128 + vch * 8);
                acc_o[0][jo] = __builtin_amdgcn_mfma_f32_16x16x32_bf16(pa[0].s8, bv, acc_o[0][jo], 0, 0, 0);
                acc_o[1][jo] = __builtin_amdgcn_mfma_f32_16x16x32_bf16(pa[1].s8, bv, acc_o[1][jo], 0, 0, 0);
            }
        }
        __builtin_amdgcn_s_setprio(0);
        __syncthreads();
        if (tk < 7) stage_V(tk + 1);
    }

    // epilogue: O = acc_o / l
#pragma unroll
    for (int i = 0; i < 2; i++)
#pragma unroll
        for (int r = 0; r < 4; r++) {
            float rs = __shfl(lrow[i], quad * 4 + r);
            float rinv = 1.f / rs;
            int row = qt * 128 + w * 32 + i * 16 + quad * 4 + r;
#pragma unroll
            for (int jo = 0; jo < 4; jo++)
                O[((size_t)b * SEQ + row) * D_MODEL + h * DKV + jo * 16 + mn] =
                    f2bf(acc_o[i][jo][r] * rinv);
        }
}

// ---------------------------------------------------------------------------
// fp32 -> bf16 bulk convert
__global__ __launch_bounds__(256) void cvt_f32_bf16(const float* __restrict__ src,
                                                    ushort* __restrict__ dst) {
    size_t base = ((size_t)blockIdx.x * 256 + threadIdx.x) * 8;
    float4 a = *(const float4*)(src + base);
    float4 b = *(const float4*)(src + base + 4);
    short8 o;
    o[0] = (short)f2bf(a.x); o[1] = (short)f2bf(a.y);
    o[2] = (short)f2bf(a.z); o[3] = (short)f2bf(a.w);
    o[4] = (short)f2bf(b.x); o[5] = (short)f2bf(b.y);
    o[6] = (short)f2bf(b.z); o[7] = (short)f2bf(b.w);
    *(short8*)(dst + base) = o;
}

// x = X + positional encoding (base 1000, per reference). fp32 in, bf16 out.
__global__ __launch_bounds__(256) void add_pos(const float* __restrict__ X,
                                               ushort* __restrict__ x) {
    size_t idx = (size_t)blockIdx.x * 256 + threadIdx.x;
    int d = (int)(idx & (D_MODEL - 1));
    int s = (int)((idx >> 10) & (SEQ - 1));
    float freq = powf(1000.f, (float)(2 * (d >> 1)) * (1.f / (float)D_MODEL));
    float ang = (float)s / freq;
    float pe = (d & 1) ? cosf(ang) : sinf(ang);
    x[idx] = f2bf(X[idx] + pe);
}

// per-row sum of bf16 weight matrix rows (colsum of W^T): cs[row]=sum_k W[row][k]
__global__ __launch_bounds__(256) void colsum_k(const ushort* __restrict__ W,
                                                float* __restrict__ cs) {
    int row = blockIdx.x * 4 + (threadIdx.x >> 6);
    int lane = threadIdx.x & 63;
    const ushort* Wr = W + (size_t)row * D_MODEL;
    float s = 0.f;
#pragma unroll
    for (int p = 0; p < 2; p++) {
        short8 v = *(const short8*)(Wr + p * 512 + lane * 8);
#pragma unroll
        for (int e = 0; e < 8; e++) s += bf2f((ushort)v[e]);
    }
#pragma unroll
    for (int o = 1; o < 64; o <<= 1) s += __shfl_xor(s, o);
    if (lane == 0) cs[row] = s;
}

__global__ void zero_stats512(float* stats) {   // 8 instances x 64 floats
    stats[threadIdx.x] = 0.f; stats[256 + threadIdx.x] = 0.f;
}

// ---------------------------------------------------------------------------
extern "C" void kernel_launch(void* const* d_in, const int* in_sizes, int n_in,
                              void* d_out, int out_size, void* d_ws, size_t ws_size,
                              hipStream_t stream) {
    const float* X    = (const float*)d_in[0];
    const float* Wq   = (const float*)d_in[1];
    const float* Wk   = (const float*)d_in[2];
    const float* Wv   = (const float*)d_in[3];
    const float* W0   = (const float*)d_in[4];
    const float* Wr_w = (const float*)d_in[5];
    const float* Wr_b = (const float*)d_in[6];
    const float* Wf0w = (const float*)d_in[7];
    const float* Wf0b = (const float*)d_in[8];
    const float* Wf1w = (const float*)d_in[9];
    const float* Wf1b = (const float*)d_in[10];
    float* out = (float*)d_out;

    char* ws = (char*)d_ws;
    size_t off = 0;
    auto alloc = [&](size_t bytes) -> void* {
        void* p = ws + off; off += (bytes + 255) & ~(size_t)255; return p;
    };
    const size_t ACT = (size_t)NTOK * D_MODEL * sizeof(ushort);     // 16 MB
    const size_t WTE = (size_t)LAYERS * D_MODEL * D_MODEL;          // elements/weight tensor
    ushort* x  = (ushort*)alloc(ACT);
    ushort* bQ = (ushort*)alloc(ACT);
    ushort* bK = (ushort*)alloc(ACT);
    ushort* bV = (ushort*)alloc(ACT);   // Vt: [B][H][DK][SEQ]
    ushort* bO = (ushort*)alloc(ACT);
    ushort* wq  = (ushort*)alloc(WTE * 2);
    ushort* wk  = (ushort*)alloc(WTE * 2);
    ushort* wv  = (ushort*)alloc(WTE * 2);
    ushort* w0  = (ushort*)alloc(WTE * 2);
    ushort* wr  = (ushort*)alloc(WTE * 2);
    ushort* wf0 = (ushort*)alloc(WTE * 2);
    ushort* wf1 = (ushort*)alloc(WTE * 2);
    float* stats = (float*)alloc(8 * 64 * sizeof(float));   // 2 LN inst/layer
    float* csr   = (float*)alloc(WTE / D_MODEL * sizeof(float)); // colsum(Wr): 4096

    const int CVT_BLOCKS = (int)(WTE / (256 * 8));             // 2048
    const dim3 GEMM_GRID(NTOK / 128, D_MODEL / 128);           // (64, 8)
    const dim3 QKV_GRID(NTOK / 128, 3 * D_MODEL / 128);        // (64, 24)
    const dim3 FLASH_GRID(BATCH * HEADS, SEQ / 128);           // (128, 8)

    cvt_f32_bf16<<<CVT_BLOCKS, 256, 0, stream>>>(Wq,   wq);
    cvt_f32_bf16<<<CVT_BLOCKS, 256, 0, stream>>>(Wk,   wk);
    cvt_f32_bf16<<<CVT_BLOCKS, 256, 0, stream>>>(Wv,   wv);
    cvt_f32_bf16<<<CVT_BLOCKS, 256, 0, stream>>>(W0,   w0);
    cvt_f32_bf16<<<CVT_BLOCKS, 256, 0, stream>>>(Wr_w, wr);
    cvt_f32_bf16<<<CVT_BLOCKS, 256, 0, stream>>>(Wf0w, wf0);
    cvt_f32_bf16<<<CVT_BLOCKS, 256, 0, stream>>>(Wf1w, wf1);
    colsum_k<<<LAYERS * D_MODEL / 4, 256, 0, stream>>>(wr, csr);
    zero_stats512<<<1, 256, 0, stream>>>(stats);

    add_pos<<<(NTOK * D_MODEL) / 256, 256, 0, stream>>>(X, x);

    for (int l = 0; l < LAYERS; l++) {
        const size_t WO = (size_t)l * D_MODEL * D_MODEL;
        const ushort* Wq_l  = wq  + WO;
        const ushort* Wk_l  = wk  + WO;
        const ushort* Wv_l  = wv  + WO;
        const ushort* W0_l  = w0  + WO;
        const ushort* Wr_l  = wr  + WO;
        const ushort* W0w_l = wf0 + WO;
        const ushort* W1w_l = wf1 + WO;
        const float* Wrb_l = Wr_b + (size_t)l * D_MODEL;
        const float* W0b_l = Wf0b + (size_t)l * D_MODEL;
        const float* W1b_l = Wf1b + (size_t)l * D_MODEL;
        const float* cs_l  = csr + (size_t)l * D_MODEL;
        float* st0 = stats + (size_t)(2 * l) * 64;
        float* st1 = stats + (size_t)(2 * l + 1) * 64;

        // Q,K,V projections (fused; Q pre-scaled by 1/8)
        gemm_qkv<<<QKV_GRID, 256, 0, stream>>>(x, Wq_l, Wk_l, Wv_l, bQ, bK, bV);

        flash_attn<<<FLASH_GRID, 256, 0, stream>>>(bQ, bK, bV, bO);

        // s1 = x + O@W0^T -> bK (bf16) + LN stats (inst 2l)
        gemm_bt128<<<GEMM_GRID, 256, 0, stream>>>(bO, W0_l, nullptr, bK,
            x, st0, nullptr, 0, nullptr, nullptr);
        // r0 = LN(s1) @ Wr^T + br -> bV   (algebraic LN via st0 + colsum)
        gemm_bt128<<<GEMM_GRID, 256, 0, stream>>>(bK, Wr_l, Wrb_l, bV,
            nullptr, nullptr, nullptr, 0, st0, cs_l);
        // h0 = relu(r0 @ Wf0^T + b0) -> bQ
        gemm_bt128<<<GEMM_GRID, 256, 0, stream>>>(bV, W0w_l, W0b_l, bQ,
            nullptr, nullptr, nullptr, 1, nullptr, nullptr);
        // s2 = r0 + h0 @ Wf1^T + b1 -> bO + LN stats (inst 2l+1)
        gemm_bt128<<<GEMM_GRID, 256, 0, stream>>>(bQ, W1w_l, W1b_l, bO,
            bV, st1, nullptr, 0, nullptr, nullptr);
        // x = LN(s2) @ Wr^T + br -> x (last layer: fp32 straight to d_out)
        gemm_bt128<<<GEMM_GRID, 256, 0, stream>>>(bO, Wr_l, Wrb_l, x,
            nullptr, nullptr, (l == LAYERS - 1) ? out : nullptr, 0, st1, cs_l);
    }
}